// Round 5
// baseline (303.761 us; speedup 1.0000x reference)
//
#include <hip/hip_runtime.h>
#include <hip/hip_bf16.h>

#define VOCAB 32000
#define DIM 64
#define NB 16
#define SEQ 2048

typedef __attribute__((ext_vector_type(8))) short bf16x8;   // 8 bf16 in 4 VGPRs
typedef __attribute__((ext_vector_type(4))) float f32x4;

// round-to-nearest-even fp32 -> bf16 (inputs are finite normals; no NaN care)
__device__ __forceinline__ unsigned short f2bf(float f) {
    unsigned int u = __builtin_bit_cast(unsigned int, f);
    u = (u + 0x7fffu + ((u >> 16) & 1u)) >> 16;
    return (unsigned short)u;
}

// Gather weight rows per token and convert to bf16.
// One thread per 8 elements: 16*2048 tokens * 8 chunks = 262144 threads.
__global__ __launch_bounds__(256) void gather_cvt(
        const int* __restrict__ seq,
        const float* __restrict__ weight,
        unsigned short* __restrict__ embs) {
    int tid = blockIdx.x * 256 + threadIdx.x;
    int token = tid >> 3;
    int c = (tid & 7) * 8;
    int row = seq[token];
    const float* src = weight + (size_t)row * DIM + c;
    unsigned short o[8];
#pragma unroll
    for (int j = 0; j < 8; ++j) o[j] = f2bf(src[j]);
    *reinterpret_cast<bf16x8*>(embs + (size_t)token * DIM + c) =
        *reinterpret_cast<bf16x8*>(o);
}

// Per batch: C = E * E^T / 8, M=N=2048, K=64.
// STREAMING-WRITE design: the write stream is the proven bottleneck
// (rounds 0-4: store pattern and compute halving both neutral; all prior
// variants ran at <=3 waves/SIMD). This kernel maximizes write
// concurrency, replicating the regime of the 6.2 TB/s fill kernel:
//   - no LDS, __launch_bounds__(256,8) caps VGPR at 64 -> 8 waves/SIMD
//   - one wave = one 16-row x 512-col output strip; A-frag loaded once
//   - loop over 32 n-tiles: 2 B-frag loads (L2-resident embs), 2 MFMA,
//     4 dword stores -> stores issue continuously, rows written
//     sequentially left-to-right (page-friendly), 8192 waves in flight
// Fragment layouts (verified learn_hip m89/m91/m120):
//   A[m=lane&15][k=(lane>>4)*8+j], B[k=(lane>>4)*8+j][n=lane&15]
//   C: col=lane&15, row=(lane>>4)*4+reg
__global__ __launch_bounds__(256, 8) void synergy_gemm(
        const unsigned short* __restrict__ embs,
        float* __restrict__ out) {
    const int b     = blockIdx.y;
    const int strip = blockIdx.x;            // which 16-row strip of C
    const int wave  = threadIdx.x >> 6;
    const int lane  = threadIdx.x & 63;
    const int r     = lane & 15;
    const int q     = lane >> 4;
    const int m0    = strip * 16;
    const int nc0   = wave * 512;            // wave's column segment

    const unsigned short* eb = embs + (size_t)b * SEQ * DIM;

    // A fragment: rows m0..m0+15; lane reads row m0+r, k = q*8..q*8+7, +32
    const unsigned short* pa = eb + (size_t)(m0 + r) * DIM + q * 8;
    const bf16x8 a0 = *reinterpret_cast<const bf16x8*>(pa);
    const bf16x8 a1 = *reinterpret_cast<const bf16x8*>(pa + 32);

    // B fragment source: C-col n = nc0 + it*16 + r  ->  embs row n
    const unsigned short* pb = eb + (size_t)(nc0 + r) * DIM + q * 8;

    // Output: lane stores C[m0+q*4+reg][nc0+it*16+r] for reg 0..3
    float* o = out + (size_t)b * SEQ * SEQ + (size_t)(m0 + q * 4) * SEQ
                   + nc0 + r;

#pragma unroll 4
    for (int it = 0; it < 32; ++it) {
        bf16x8 b0 = *reinterpret_cast<const bf16x8*>(pb);
        bf16x8 b1 = *reinterpret_cast<const bf16x8*>(pb + 32);
        f32x4 c = {0.f, 0.f, 0.f, 0.f};
        c = __builtin_amdgcn_mfma_f32_16x16x32_bf16(a0, b0, c, 0, 0, 0);
        c = __builtin_amdgcn_mfma_f32_16x16x32_bf16(a1, b1, c, 0, 0, 0);
        float* oc = o + it * 16;
#pragma unroll
        for (int reg = 0; reg < 4; ++reg)
            oc[(size_t)reg * SEQ] = c[reg] * 0.125f;
        pb += 16 * DIM;                      // next 16 C-cols = next 16 E-rows
    }
}

extern "C" void kernel_launch(void* const* d_in, const int* in_sizes, int n_in,
                              void* d_out, int out_size, void* d_ws, size_t ws_size,
                              hipStream_t stream) {
    const int*   seq    = (const int*)d_in[0];     // [16,2048] int32
    const float* weight = (const float*)d_in[1];   // [32000,64] fp32
    float*       out    = (float*)d_out;           // [16,2048,2048] fp32
    unsigned short* embs = (unsigned short*)d_ws;  // [16,2048,64] bf16 = 4 MiB

    // gather+cvt: 262144 threads
    gather_cvt<<<dim3(262144 / 256), dim3(256), 0, stream>>>(seq, weight, embs);

    // GEMM: grid (row-strips, batch); 2048 blocks x 4 waves = 8192 waves
    synergy_gemm<<<dim3(SEQ / 16, NB), dim3(256), 0, stream>>>(embs, out);
}

// Round 6
// 281.010 us; speedup vs baseline: 1.0810x; 1.0810x over previous
//
#include <hip/hip_runtime.h>
#include <hip/hip_bf16.h>

#define VOCAB 32000
#define DIM 64
#define NB 16
#define SEQ 2048

typedef __attribute__((ext_vector_type(8))) short bf16x8;   // 8 bf16 in 4 VGPRs
typedef __attribute__((ext_vector_type(4))) float f32x4;

// round-to-nearest-even fp32 -> bf16 (inputs are finite normals; no NaN care)
__device__ __forceinline__ unsigned short f2bf(float f) {
    unsigned int u = __builtin_bit_cast(unsigned int, f);
    u = (u + 0x7fffu + ((u >> 16) & 1u)) >> 16;
    return (unsigned short)u;
}

// Gather weight rows per token and convert to bf16.
// One thread per 8 elements: 16*2048 tokens * 8 chunks = 262144 threads.
__global__ __launch_bounds__(256) void gather_cvt(
        const int* __restrict__ seq,
        const float* __restrict__ weight,
        unsigned short* __restrict__ embs) {
    int tid = blockIdx.x * 256 + threadIdx.x;
    int token = tid >> 3;
    int c = (tid & 7) * 8;
    int row = seq[token];
    const float* src = weight + (size_t)row * DIM + c;
    unsigned short o[8];
#pragma unroll
    for (int j = 0; j < 8; ++j) o[j] = f2bf(src[j]);
    *reinterpret_cast<bf16x8*>(embs + (size_t)token * DIM + c) =
        *reinterpret_cast<bf16x8*>(o);
}

// Per batch: C = E * E^T / 8, M=N=2048, K=64 (single k-tile).
// Structure IDENTICAL to round 3 (measured 283.4us) except all output
// stores are NON-TEMPORAL. Theory: default write-allocate stores cycle
// the 268MB output stream through the 4MiB/XCD L2, evicting embs (4MiB)
// and contending with read misses in the TCC; the 6.2TB/s fill kernel
// pays nothing for write-allocate because it has no read working set.
// NT stores (no L2 allocation) were only ever tested confounded with a
// bad wide tile (round 2); this isolates the variable.
//
// Block = 128x128 tile, 4 waves, wave w computes rows [m0w, m0w+32).
// C = E*E^T is bit-exactly symmetric, so the block stores its tile
// TRANSPOSED via per-wave LDS tile T[128][36]; readback stores full
// 128B lines per instruction (verified round 3).
__global__ __launch_bounds__(256) void synergy_gemm(
        const unsigned short* __restrict__ embs,
        float* __restrict__ out) {
    const int b    = blockIdx.z;
    const int n0   = blockIdx.x * 128;
    const int wave = threadIdx.x >> 6;
    const int lane = threadIdx.x & 63;
    const int m0   = blockIdx.y * 128 + wave * 32;
    const int r    = lane & 15;
    const int q    = lane >> 4;

    __shared__ float lds[4][128][36];   // 72 KiB, wave-private slabs
    float* T = &lds[wave][0][0];

    const unsigned short* eb = embs + (size_t)b * SEQ * DIM;

    bf16x8 a[2][2], bv[8][2];
#pragma unroll
    for (int mt = 0; mt < 2; ++mt) {
        const unsigned short* p = eb + (size_t)(m0 + mt * 16 + r) * DIM + q * 8;
        a[mt][0] = *reinterpret_cast<const bf16x8*>(p);
        a[mt][1] = *reinterpret_cast<const bf16x8*>(p + 32);
    }
#pragma unroll
    for (int nt = 0; nt < 8; ++nt) {
        const unsigned short* p = eb + (size_t)(n0 + nt * 16 + r) * DIM + q * 8;
        bv[nt][0] = *reinterpret_cast<const bf16x8*>(p);
        bv[nt][1] = *reinterpret_cast<const bf16x8*>(p + 32);
    }

    f32x4 acc[2][8];
#pragma unroll
    for (int mt = 0; mt < 2; ++mt)
#pragma unroll
        for (int nt = 0; nt < 8; ++nt) {
            f32x4 c = {0.f, 0.f, 0.f, 0.f};
            c = __builtin_amdgcn_mfma_f32_16x16x32_bf16(a[mt][0], bv[nt][0], c, 0, 0, 0);
            c = __builtin_amdgcn_mfma_f32_16x16x32_bf16(a[mt][1], bv[nt][1], c, 0, 0, 0);
            acc[mt][nt] = c;
        }

    // Stage transposed+scaled fragments into LDS.
    // acc[mt][nt][reg] = C[m0+mt*16+q*4+reg][n0+nt*16+r]
    //   -> T[nt*16+r][mt*16+q*4+reg]
#pragma unroll
    for (int nt = 0; nt < 8; ++nt)
#pragma unroll
        for (int mt = 0; mt < 2; ++mt) {
            f32x4 v = acc[mt][nt] * 0.125f;
            *reinterpret_cast<f32x4*>(T + (nt * 16 + r) * 36 + mt * 16 + q * 4) = v;
        }

    __syncthreads();

    // Read back row-major and store full 128B lines, NON-TEMPORAL.
    // Wave's transposed tile: global rows [n0, n0+128) x cols [m0, m0+32).
    const int h = lane >> 3;        // 0..7  (row within 8-row group)
    const int l = lane & 7;         // 0..7  (16B column chunk)
    float* ob = out + (size_t)b * SEQ * SEQ + (size_t)m0 + (size_t)l * 4;
#pragma unroll
    for (int chunk = 0; chunk < 16; ++chunk) {
        int trow = chunk * 8 + h;
        f32x4 v = *reinterpret_cast<f32x4*>(T + trow * 36 + l * 4);
        __builtin_nontemporal_store(
            v, reinterpret_cast<f32x4*>(ob + (size_t)(n0 + trow) * SEQ));
    }
}

extern "C" void kernel_launch(void* const* d_in, const int* in_sizes, int n_in,
                              void* d_out, int out_size, void* d_ws, size_t ws_size,
                              hipStream_t stream) {
    const int*   seq    = (const int*)d_in[0];     // [16,2048] int32
    const float* weight = (const float*)d_in[1];   // [32000,64] fp32
    float*       out    = (float*)d_out;           // [16,2048,2048] fp32
    unsigned short* embs = (unsigned short*)d_ws;  // [16,2048,64] bf16 = 4 MiB

    // gather+cvt: 262144 threads
    gather_cvt<<<dim3(262144 / 256), dim3(256), 0, stream>>>(seq, weight, embs);

    // GEMM: grid (n-tiles, m-tiles, batch)
    synergy_gemm<<<dim3(SEQ / 128, SEQ / 128, NB), dim3(256), 0, stream>>>(embs, out);
}